// Round 15
// baseline (443.971 us; speedup 1.0000x reference)
//
#include <hip/hip_runtime.h>
#include <hip/hip_bf16.h>
#include <stdint.h>
#include <stddef.h>

#define N_ 50000
#define E_ 600000
#define F_ 128
#define H_ 128
#define G_ 64
#define P_ 32
#define C_ 10
#define NB_ 49   // scan blocks: ceil(N/1024)

typedef __hip_bfloat16 bf16;
typedef __attribute__((ext_vector_type(8))) short short8;
typedef __attribute__((ext_vector_type(4))) float float4v;

__device__ __forceinline__ float b2f(bf16 x){ return __bfloat162float(x); }
__device__ __forceinline__ float us2f(unsigned short u){ return __uint_as_float(((unsigned int)u)<<16); }
__device__ __forceinline__ unsigned short f2us(float x){ bf16 h = __float2bfloat16(x); return *(unsigned short*)&h; }
__device__ __forceinline__ float eluf(float x){ return x>0.f ? x : expm1f(x); }
__device__ __forceinline__ float bnf(float x,float m,float v,float g,float b){ return (x-m)*rsqrtf(v+1e-5f)*g+b; }
__device__ __forceinline__ float lrelu(float x){ return x>0.f ? x : 0.2f*x; }
__device__ __forceinline__ float expc(float x){ return __expf(fminf(x, 50.f)); }
__device__ __forceinline__ void atomAddF(float* a, float v){ unsafeAtomicAdd(a, v); }

// ---------------- weight prep: WT[m][n][k] (bf16) = W_m[k][n] ----------------
__global__ __launch_bounds__(256) void k_wprep(const float* __restrict__ W1, const float* __restrict__ Wl,
    const float* __restrict__ Wr, const float* __restrict__ Wg, unsigned short* __restrict__ WT){
  int idx = blockIdx.x*256 + threadIdx.x;
  if(idx >= 6*16384) return;
  int m = idx >> 14, rem = idx & 16383;
  int n = rem >> 7, k = rem & 127;
  float v;
  if(m==0)      v = W1[k*128+n];
  else if(m==1) v = Wl[k*128+n];
  else if(m==2) v = Wr[k*128+n];
  else          v = Wg[k*384 + (m-3)*128 + n];
  WT[idx] = f2us(v);
}

// ---------------- MFMA GEMM helpers ----------------
__device__ __forceinline__ void stage_WT(const unsigned short* __restrict__ WTg, unsigned short* lds, int tid){
  #pragma unroll
  for(int i=0;i<8;i++){
    int idx = tid + i*256;
    int n = idx>>4, c = idx&15;
    uint4 v = *(const uint4*)(WTg + (size_t)idx*8);
    int cs = c ^ (n & 15);
    *(uint4*)(lds + n*128 + cs*8) = v;
  }
}
__device__ __forceinline__ short8 read_Bfrag(const unsigned short* lds, int tile, int kc, int lane){
  int n = tile*16 + (lane&15);
  int c = kc*4 + (lane>>4);
  int cs = c ^ (lane & 15);
  return *(const short8*)(lds + n*128 + cs*8);
}
__device__ __forceinline__ void load_Afrag_bf16(const bf16* A, int row, int lane, short8 af[4]){
  const unsigned short* ap = (const unsigned short*)A + (size_t)row*128 + (lane>>4)*8;
  #pragma unroll
  for(int kc=0;kc<4;kc++) af[kc] = *(const short8*)(ap + kc*32);
}
__device__ __forceinline__ void mfma_pass(const unsigned short* lds, const short8 af[4], int lane, float4v acc[8]){
  #pragma unroll
  for(int tile=0;tile<8;tile++){
    #pragma unroll
    for(int kc=0;kc<4;kc++){
      short8 bfv = read_Bfrag(lds, tile, kc, lane);
      acc[tile] = __builtin_amdgcn_mfma_f32_16x16x32_bf16(af[kc], bfv, acc[tile], 0, 0, 0);
    }
  }
}

// h(bf16) = X(f32) @ W1
__global__ __launch_bounds__(256) void k_mm_x(const float* __restrict__ X, const unsigned short* __restrict__ WTg,
                                              bf16* __restrict__ HB){
  __shared__ unsigned short Wlds[128*128];
  const int tid = threadIdx.x, lane = tid&63, w = tid>>6;
  const int row0 = blockIdx.x*64;
  stage_WT(WTg, Wlds, tid);
  int arow = row0 + w*16 + (lane&15);
  int ar = arow < N_ ? arow : N_-1;
  const float* ap = X + (size_t)ar*128 + (lane>>4)*8;
  short8 af[4];
  #pragma unroll
  for(int kc=0;kc<4;kc++){
    float4 a = *(const float4*)(ap + kc*32);
    float4 b = *(const float4*)(ap + kc*32 + 4);
    short8 v;
    v[0]=(short)f2us(a.x); v[1]=(short)f2us(a.y); v[2]=(short)f2us(a.z); v[3]=(short)f2us(a.w);
    v[4]=(short)f2us(b.x); v[5]=(short)f2us(b.y); v[6]=(short)f2us(b.z); v[7]=(short)f2us(b.w);
    af[kc]=v;
  }
  __syncthreads();
  float4v acc[8];
  #pragma unroll
  for(int t=0;t<8;t++){ acc[t][0]=0.f; acc[t][1]=0.f; acc[t][2]=0.f; acc[t][3]=0.f; }
  mfma_pass(Wlds, af, lane, acc);
  const int colb = lane&15, q = lane>>4;
  unsigned short* ob = (unsigned short*)HB;
  #pragma unroll
  for(int r=0;r<4;r++){
    int ro = row0 + w*16 + q*4 + r;
    if(ro < N_){
      #pragma unroll
      for(int tile=0;tile<8;tile++)
        ob[(size_t)ro*128 + tile*16 + colb] = f2us(acc[tile][r]);
    }
  }
}

// h2(bf16) = elu(bn2( mean@Wl + h1@Wr + bs ))
__global__ __launch_bounds__(256) void k_sage_mm(const bf16* __restrict__ MaB, const bf16* __restrict__ H1B,
    const unsigned short* __restrict__ WlT, const unsigned short* __restrict__ WrT,
    const float* __restrict__ bs, const float* __restrict__ g2, const float* __restrict__ be2,
    const float* __restrict__ m2, const float* __restrict__ v2, bf16* __restrict__ H2B){
  __shared__ unsigned short Wlds[128*128];
  const int tid = threadIdx.x, lane = tid&63, w = tid>>6;
  const int row0 = blockIdx.x*64;
  int arow = row0 + w*16 + (lane&15);
  int ar = arow < N_ ? arow : N_-1;
  float4v acc[8];
  #pragma unroll
  for(int t=0;t<8;t++){ acc[t][0]=0.f; acc[t][1]=0.f; acc[t][2]=0.f; acc[t][3]=0.f; }
  short8 af[4];

  stage_WT(WlT, Wlds, tid);
  load_Afrag_bf16(MaB, ar, lane, af);
  __syncthreads();
  mfma_pass(Wlds, af, lane, acc);
  __syncthreads();
  stage_WT(WrT, Wlds, tid);
  load_Afrag_bf16(H1B, ar, lane, af);
  __syncthreads();
  mfma_pass(Wlds, af, lane, acc);

  const int colb = lane&15, q = lane>>4;
  unsigned short* ob = (unsigned short*)H2B;
  #pragma unroll
  for(int tile=0;tile<8;tile++){
    int col = tile*16 + colb;
    float bsv=bs[col], gv=g2[col], bev=be2[col], mv=m2[col], vv=v2[col];
    #pragma unroll
    for(int r=0;r<4;r++){
      int ro = row0 + w*16 + q*4 + r;
      if(ro < N_){
        float x = acc[tile][r] + bsv;
        ob[(size_t)ro*128 + col] = f2us(eluf(bnf(x, mv, vv, gv, bev)));
      }
    }
  }
}

// HG3[n][hh][128](bf16) = h2 @ Wg_hh for all 3 heads; fused logits -> als3/ald3[n*3+hh]
__global__ __launch_bounds__(256) void k_gat_mm_all(const bf16* __restrict__ H2B, const unsigned short* __restrict__ WgT,
    const float* __restrict__ a_src, const float* __restrict__ a_dst,
    bf16* __restrict__ HG3, float* __restrict__ als3, float* __restrict__ ald3){
  __shared__ unsigned short Wlds[128*128];
  const int tid = threadIdx.x, lane = tid&63, w = tid>>6;
  const int row0 = blockIdx.x*64;
  int arow = row0 + w*16 + (lane&15);
  int ar = arow < N_ ? arow : N_-1;
  short8 af[4];
  load_Afrag_bf16(H2B, ar, lane, af);
  const int colb = lane&15, q = lane>>4;
  unsigned short* ob = (unsigned short*)HG3;
  for(int hh=0; hh<3; hh++){
    if(hh) __syncthreads();
    stage_WT(WgT + hh*16384, Wlds, tid);
    __syncthreads();
    float4v acc[8];
    #pragma unroll
    for(int t=0;t<8;t++){ acc[t][0]=0.f; acc[t][1]=0.f; acc[t][2]=0.f; acc[t][3]=0.f; }
    mfma_pass(Wlds, af, lane, acc);
    float asv[8], adv[8];
    #pragma unroll
    for(int tile=0;tile<8;tile++){
      asv[tile] = a_src[hh*128 + tile*16 + colb];
      adv[tile] = a_dst[hh*128 + tile*16 + colb];
    }
    #pragma unroll
    for(int r=0;r<4;r++){
      int ro = row0 + w*16 + q*4 + r;
      float ps = 0.f, pd = 0.f;
      #pragma unroll
      for(int tile=0;tile<8;tile++){ ps += acc[tile][r]*asv[tile]; pd += acc[tile][r]*adv[tile]; }
      #pragma unroll
      for(int o=8;o>0;o>>=1){ ps += __shfl_down(ps,o,16); pd += __shfl_down(pd,o,16); }
      if(ro < N_){
        #pragma unroll
        for(int tile=0;tile<8;tile++)
          ob[(size_t)ro*384 + hh*128 + tile*16 + colb] = f2us(acc[tile][r]);
        if(colb == 0){ als3[ro*3+hh] = ps; ald3[ro*3+hh] = pd; }
      }
    }
  }
}

// ---------------- CSR build ----------------
__global__ __launch_bounds__(256) void k_count(const int* __restrict__ dst, int* __restrict__ cnt){
  int e = blockIdx.x*256 + threadIdx.x;
  if(e < E_) atomicAdd(&cnt[dst[e]], 1);
}

__global__ __launch_bounds__(1024) void k_scan1(const int* __restrict__ cnt, int* __restrict__ row_ptr,
                                                float* __restrict__ dinv, int* __restrict__ bsum){
  __shared__ int wsum[16];
  const int t = threadIdx.x, lane = t & 63, wid = t >> 6;
  int i = blockIdx.x*1024 + t;
  int v = (i<N_) ? cnt[i] : 0;
  int x = v;
  #pragma unroll
  for(int o=1;o<64;o<<=1){
    int y = __shfl_up(x, o, 64);
    if(lane >= o) x += y;
  }
  if(lane==63) wsum[wid] = x;
  __syncthreads();
  if(wid==0){
    int s = (lane<16) ? wsum[lane] : 0;
    #pragma unroll
    for(int o=1;o<16;o<<=1){
      int y = __shfl_up(s, o, 64);
      if(lane >= o) s += y;
    }
    if(lane<16) wsum[lane] = s;
  }
  __syncthreads();
  int waveoff = (wid>0) ? wsum[wid-1] : 0;
  int incl = waveoff + x;
  if(i<N_){
    row_ptr[i] = incl - v;
    dinv[i] = rsqrtf((float)v + 1.f);
  }
  if(t==1023) bsum[blockIdx.x] = incl;
}

__global__ __launch_bounds__(64) void k_scan2(const int* __restrict__ bsum, int* __restrict__ boff,
                                              int* __restrict__ row_ptr){
  int lane = threadIdx.x;
  int v = (lane < NB_) ? bsum[lane] : 0;
  int x = v;
  #pragma unroll
  for(int o=1;o<64;o<<=1){
    int y = __shfl_up(x, o, 64);
    if(lane >= o) x += y;
  }
  if(lane < NB_) boff[lane] = x - v;
  if(lane == 63) row_ptr[N_] = x;
}

__global__ __launch_bounds__(256) void k_scan3(int* __restrict__ row_ptr, const int* __restrict__ boff,
                                               int* __restrict__ tmp){
  int i = blockIdx.x*256 + threadIdx.x;
  if(i < N_){
    int r = row_ptr[i] + boff[i>>10];
    row_ptr[i] = r;
    tmp[i] = r;
  }
}

// scatter: also emit edst and GCN coefficient cg = dinv[s]*dinv[d]
__global__ __launch_bounds__(256) void k_scatter(const int* __restrict__ src, const int* __restrict__ dst,
    const float* __restrict__ dinv, int* __restrict__ tmp,
    int* __restrict__ esrc, int* __restrict__ edst, float* __restrict__ cg){
  int e = blockIdx.x*256 + threadIdx.x;
  if(e < E_){
    int s = src[e], d = dst[e];
    int pos = atomicAdd(&tmp[d], 1);
    esrc[pos] = s;
    edst[pos] = d;
    cg[pos] = dinv[s]*dinv[d];
  }
}

// edge weights for GAT: ew3[e*3+h] = exp(lrelu(als3[s]+ald3[d])) — computed once per edge
__global__ __launch_bounds__(256) void k_ew(const int* __restrict__ esrc, const int* __restrict__ edst,
    const float* __restrict__ als3, const float* __restrict__ ald3, float* __restrict__ ew3){
  int e = blockIdx.x*256 + threadIdx.x;
  if(e < E_){
    int s = esrc[e], d = edst[e];
    ew3[e*3+0] = expc(lrelu(als3[s*3+0] + ald3[d*3+0]));
    ew3[e*3+1] = expc(lrelu(als3[s*3+1] + ald3[d*3+1]));
    ew3[e*3+2] = expc(lrelu(als3[s*3+2] + ald3[d*3+2]));
  }
}

// ---------------- CSR gather kernels ----------------
__global__ __launch_bounds__(256) void k_gcn_gather(const int* __restrict__ row_ptr, const int* __restrict__ esrc,
    const float* __restrict__ cg, const float* __restrict__ dinv, const bf16* __restrict__ HB,
    const float* __restrict__ b1, const float* __restrict__ g1, const float* __restrict__ be1,
    const float* __restrict__ m1, const float* __restrict__ v1, bf16* __restrict__ H1B){
  int n = blockIdx.x*4 + (threadIdx.x>>6);
  int lane = threadIdx.x & 63;
  if(n >= N_) return;
  int beg = row_ptr[n], end = row_ptr[n+1];
  float dn = dinv[n];
  float a0 = 0.f, a1 = 0.f;
  const unsigned short* hb = (const unsigned short*)HB;
  int e = beg;
  for(; e+3 < end; e += 4){
    int s0 = esrc[e], s1 = esrc[e+1], s2 = esrc[e+2], s3 = esrc[e+3];
    unsigned int hv0 = *(const unsigned int*)(hb + (size_t)s0*H_ + lane*2);
    unsigned int hv1 = *(const unsigned int*)(hb + (size_t)s1*H_ + lane*2);
    unsigned int hv2 = *(const unsigned int*)(hb + (size_t)s2*H_ + lane*2);
    unsigned int hv3 = *(const unsigned int*)(hb + (size_t)s3*H_ + lane*2);
    float c0 = cg[e], c1 = cg[e+1], c2 = cg[e+2], c3 = cg[e+3];
    a0 += c0*us2f((unsigned short)(hv0 & 0xFFFFu)) + c1*us2f((unsigned short)(hv1 & 0xFFFFu))
        + c2*us2f((unsigned short)(hv2 & 0xFFFFu)) + c3*us2f((unsigned short)(hv3 & 0xFFFFu));
    a1 += c0*us2f((unsigned short)(hv0 >> 16)) + c1*us2f((unsigned short)(hv1 >> 16))
        + c2*us2f((unsigned short)(hv2 >> 16)) + c3*us2f((unsigned short)(hv3 >> 16));
  }
  for(; e < end; e++){
    int s = esrc[e];
    float c = cg[e];
    unsigned int hv = *(const unsigned int*)(hb + (size_t)s*H_ + lane*2);
    a0 += c*us2f((unsigned short)(hv & 0xFFFFu));
    a1 += c*us2f((unsigned short)(hv >> 16));
  }
  unsigned int hv = *(const unsigned int*)(hb + (size_t)n*H_ + lane*2);
  int f0 = lane*2, f1 = f0+1;
  float x0 = a0 + us2f((unsigned short)(hv & 0xFFFFu))*dn*dn + b1[f0];
  float x1 = a1 + us2f((unsigned short)(hv >> 16))*dn*dn + b1[f1];
  x0 = eluf(bnf(x0, m1[f0], v1[f0], g1[f0], be1[f0]));
  x1 = eluf(bnf(x1, m1[f1], v1[f1], g1[f1], be1[f1]));
  unsigned int o = ((unsigned int)f2us(x1)<<16) | f2us(x0);
  *(unsigned int*)((unsigned short*)H1B + (size_t)n*H_ + lane*2) = o;
}

__global__ __launch_bounds__(256) void k_sage_gather(const int* __restrict__ row_ptr, const int* __restrict__ esrc,
    const bf16* __restrict__ H1B, bf16* __restrict__ MeanB){
  int n = blockIdx.x*4 + (threadIdx.x>>6);
  int lane = threadIdx.x & 63;
  if(n >= N_) return;
  int beg = row_ptr[n], end = row_ptr[n+1];
  float a0 = 0.f, a1 = 0.f;
  const unsigned short* hb = (const unsigned short*)H1B;
  int e = beg;
  for(; e+3 < end; e += 4){
    int s0 = esrc[e], s1 = esrc[e+1], s2 = esrc[e+2], s3 = esrc[e+3];
    unsigned int hv0 = *(const unsigned int*)(hb + (size_t)s0*H_ + lane*2);
    unsigned int hv1 = *(const unsigned int*)(hb + (size_t)s1*H_ + lane*2);
    unsigned int hv2 = *(const unsigned int*)(hb + (size_t)s2*H_ + lane*2);
    unsigned int hv3 = *(const unsigned int*)(hb + (size_t)s3*H_ + lane*2);
    a0 += us2f((unsigned short)(hv0 & 0xFFFFu)) + us2f((unsigned short)(hv1 & 0xFFFFu))
        + us2f((unsigned short)(hv2 & 0xFFFFu)) + us2f((unsigned short)(hv3 & 0xFFFFu));
    a1 += us2f((unsigned short)(hv0 >> 16)) + us2f((unsigned short)(hv1 >> 16))
        + us2f((unsigned short)(hv2 >> 16)) + us2f((unsigned short)(hv3 >> 16));
  }
  for(; e < end; e++){
    unsigned int hv = *(const unsigned int*)(hb + (size_t)esrc[e]*H_ + lane*2);
    a0 += us2f((unsigned short)(hv & 0xFFFFu));
    a1 += us2f((unsigned short)(hv >> 16));
  }
  float inv = 1.f / fmaxf((float)(end-beg), 1.f);
  unsigned int o = ((unsigned int)f2us(a1*inv)<<16) | f2us(a0*inv);
  *(unsigned int*)((unsigned short*)MeanB + (size_t)n*H_ + lane*2) = o;
}

// GAT gather, all 3 heads, precomputed edge weights
__global__ __launch_bounds__(256) void k_gat_gather3(const int* __restrict__ row_ptr, const int* __restrict__ esrc,
    const float* __restrict__ ew3, const float* __restrict__ als3, const float* __restrict__ ald3,
    const bf16* __restrict__ HG3, bf16* __restrict__ H3B){
  int n = blockIdx.x*4 + (threadIdx.x>>6);
  int lane = threadIdx.x & 63;
  if(n >= N_) return;
  int beg = row_ptr[n], end = row_ptr[n+1];
  float es0 = expc(lrelu(als3[n*3+0] + ald3[n*3+0]));
  float es1 = expc(lrelu(als3[n*3+1] + ald3[n*3+1]));
  float es2 = expc(lrelu(als3[n*3+2] + ald3[n*3+2]));
  const unsigned short* hb = (const unsigned short*)HG3;
  size_t nb = (size_t)n*384 + lane*2;
  unsigned int h0 = *(const unsigned int*)(hb + nb);
  unsigned int h1 = *(const unsigned int*)(hb + nb + 128);
  unsigned int h2 = *(const unsigned int*)(hb + nb + 256);
  float den0 = es0, den1 = es1, den2 = es2;
  float a00 = es0*us2f((unsigned short)(h0 & 0xFFFFu)), a01 = es0*us2f((unsigned short)(h0 >> 16));
  float a10 = es1*us2f((unsigned short)(h1 & 0xFFFFu)), a11 = es1*us2f((unsigned short)(h1 >> 16));
  float a20 = es2*us2f((unsigned short)(h2 & 0xFFFFu)), a21 = es2*us2f((unsigned short)(h2 >> 16));
  int e = beg;
  for(; e+1 < end; e += 2){
    int s0 = esrc[e], s1 = esrc[e+1];
    size_t b0 = (size_t)s0*384 + lane*2, b1 = (size_t)s1*384 + lane*2;
    unsigned int p00 = *(const unsigned int*)(hb + b0);
    unsigned int p01 = *(const unsigned int*)(hb + b0 + 128);
    unsigned int p02 = *(const unsigned int*)(hb + b0 + 256);
    unsigned int p10 = *(const unsigned int*)(hb + b1);
    unsigned int p11 = *(const unsigned int*)(hb + b1 + 128);
    unsigned int p12 = *(const unsigned int*)(hb + b1 + 256);
    float w00 = ew3[e*3+0], w01 = ew3[e*3+1], w02 = ew3[e*3+2];
    float w10 = ew3[e*3+3], w11 = ew3[e*3+4], w12 = ew3[e*3+5];
    den0 += w00 + w10; den1 += w01 + w11; den2 += w02 + w12;
    a00 += w00*us2f((unsigned short)(p00 & 0xFFFFu)) + w10*us2f((unsigned short)(p10 & 0xFFFFu));
    a01 += w00*us2f((unsigned short)(p00 >> 16))     + w10*us2f((unsigned short)(p10 >> 16));
    a10 += w01*us2f((unsigned short)(p01 & 0xFFFFu)) + w11*us2f((unsigned short)(p11 & 0xFFFFu));
    a11 += w01*us2f((unsigned short)(p01 >> 16))     + w11*us2f((unsigned short)(p11 >> 16));
    a20 += w02*us2f((unsigned short)(p02 & 0xFFFFu)) + w12*us2f((unsigned short)(p12 & 0xFFFFu));
    a21 += w02*us2f((unsigned short)(p02 >> 16))     + w12*us2f((unsigned short)(p12 >> 16));
  }
  if(e < end){
    int s = esrc[e];
    size_t b0 = (size_t)s*384 + lane*2;
    unsigned int p0 = *(const unsigned int*)(hb + b0);
    unsigned int p1 = *(const unsigned int*)(hb + b0 + 128);
    unsigned int p2 = *(const unsigned int*)(hb + b0 + 256);
    float w0 = ew3[e*3+0], w1 = ew3[e*3+1], w2 = ew3[e*3+2];
    den0 += w0; den1 += w1; den2 += w2;
    a00 += w0*us2f((unsigned short)(p0 & 0xFFFFu)); a01 += w0*us2f((unsigned short)(p0 >> 16));
    a10 += w1*us2f((unsigned short)(p1 & 0xFFFFu)); a11 += w1*us2f((unsigned short)(p1 >> 16));
    a20 += w2*us2f((unsigned short)(p2 & 0xFFFFu)); a21 += w2*us2f((unsigned short)(p2 >> 16));
  }
  float i0 = 1.f/(3.f*den0), i1 = 1.f/(3.f*den1), i2 = 1.f/(3.f*den2);
  float r0 = a00*i0 + a10*i1 + a20*i2;
  float r1 = a01*i0 + a11*i1 + a21*i2;
  unsigned int o = ((unsigned int)f2us(r1)<<16) | f2us(r0);
  *(unsigned int*)((unsigned short*)H3B + (size_t)n*H_ + lane*2) = o;
}

// h3 finalize + pool
#define NPW_ 16
__global__ __launch_bounds__(256) void k_h3fin_pool(const bf16* __restrict__ ACCB, const float* __restrict__ bg,
    const float* __restrict__ g3, const float* __restrict__ be3, const float* __restrict__ m3, const float* __restrict__ v3,
    const int* __restrict__ batch, float* __restrict__ pooled, float* __restrict__ gcnt){
  int wave = blockIdx.x*4 + (threadIdx.x>>6);
  int lane = threadIdx.x & 63;
  int n0 = wave*NPW_;
  if(n0 >= N_) return;
  int n1 = n0 + NPW_; if(n1 > N_) n1 = N_;
  int f0 = lane*2, f1 = f0+1;
  float bg0=bg[f0], bg1=bg[f1];
  float g30=g3[f0], g31=g3[f1], be30=be3[f0], be31=be3[f1];
  float m30=m3[f0], m31=m3[f1], v30=v3[f0], v31=v3[f1];
  float r0=0.f, r1=0.f;
  int cur = batch[n0];
  int seg = 0;
  for(int n=n0; n<n1; n++){
    int b = batch[n];
    if(b != cur){
      atomAddF(&pooled[cur*H_ + f0], r0);
      atomAddF(&pooled[cur*H_ + f1], r1);
      if(lane==0) atomAddF(&gcnt[cur], (float)seg);
      r0 = 0.f; r1 = 0.f; seg = 0; cur = b;
    }
    unsigned int hv = *(const unsigned int*)((const unsigned short*)ACCB + (size_t)n*H_ + lane*2);
    float x0 = us2f((unsigned short)(hv & 0xFFFFu)) + bg0;
    float x1 = us2f((unsigned short)(hv >> 16)) + bg1;
    r0 += eluf(bnf(x0, m30, v30, g30, be30));
    r1 += eluf(bnf(x1, m31, v31, g31, be31));
    seg++;
  }
  atomAddF(&pooled[cur*H_ + f0], r0);
  atomAddF(&pooled[cur*H_ + f1], r1);
  if(lane==0) atomAddF(&gcnt[cur], (float)seg);
}

// per-graph head — fp32 output
__global__ __launch_bounds__(128) void k_head(const float* __restrict__ pooledacc, const float* __restrict__ gcnt,
    const float* __restrict__ protos, const float* __restrict__ Wc, const float* __restrict__ bc,
    const float* __restrict__ Wd1, const float* __restrict__ bd1, const float* __restrict__ Wd2, const float* __restrict__ bd2,
    float* __restrict__ out){
  const int g = blockIdx.x, t = threadIdx.x;
  __shared__ float p[128], xn[128], red[128], sims[32], es[32], asg[32], pe[128], t1[256];
  __shared__ float nrm;
  float cg_ = fmaxf(gcnt[g], 1.f);
  p[t] = pooledacc[g*128 + t] / cg_;
  __syncthreads();
  red[t] = p[t]*p[t];
  __syncthreads();
  for(int s=64;s>0;s>>=1){ if(t<s) red[t]+=red[t+s]; __syncthreads(); }
  if(t==0) nrm = fmaxf(sqrtf(red[0]), 1e-8f);
  __syncthreads();
  xn[t] = p[t]/nrm;
  __syncthreads();
  if(t<32){
    float s=0.f, pn=0.f;
    for(int f=0;f<128;f++){ float pv=protos[t*128+f]; s += xn[f]*pv; pn += pv*pv; }
    sims[t] = s / fmaxf(sqrtf(pn), 1e-8f);
  }
  __syncthreads();
  if(t<32){
    float mx=-1e30f;
    for(int j=0;j<32;j++) mx = fmaxf(mx, sims[j]);
    es[t] = __expf(sims[t]-mx);
  }
  __syncthreads();
  if(t<32){
    float sm=0.f;
    for(int j=0;j<32;j++) sm += es[j];
    float a = es[t]/fmaxf(sm,1e-20f);
    asg[t] = a;
    out[8832 + g*32 + t] = a;
  }
  __syncthreads();
  {
    float s=0.f;
    for(int pp=0;pp<32;pp++) s += asg[pp]*protos[pp*128+t];
    pe[t] = s;
    out[640 + g*128 + t] = s;
  }
  __syncthreads();
  if(t<10){
    float s = bc[t];
    for(int f=0;f<128;f++) s += pe[f]*Wc[f*10+t];
    out[g*10 + t] = s;
  }
  for(int j=t;j<256;j+=128){
    float s = bd1[j];
    for(int f=0;f<128;f++) s += p[f]*Wd1[f*256+j];
    t1[j] = fmaxf(s, 0.f);
  }
  __syncthreads();
  {
    float s = bd2[t];
    for(int j=0;j<256;j++) s += t1[j]*Wd2[j*128+t];
    out[10880 + g*128 + t] = s;
  }
}

__global__ void k_sentinel(float* out, float code){
  out[0] = code;
}

extern "C" void kernel_launch(void* const* d_in, const int* in_sizes, int n_in,
                              void* d_out, int out_size, void* d_ws, size_t ws_size,
                              hipStream_t stream){
  const float* X    = (const float*)d_in[0];
  const int*  EI    = (const int*)d_in[1];
  const int*  batch = (const int*)d_in[2];
  const int* src = EI;
  const int* dst = EI + E_;

  int iW1,ib1,iWl,iWr,ibs,iWg,ias,iad,ibg,ipr,iWc,ibc,iWd1,ibd1,iWd2,ibd2;
  int ig1,ibe1,im1,iv1,ig2,ibe2,im2,iv2,ig3,ibe3,im3,iv3;
  if(n_in >= 31 && in_sizes[5] == 128){
    iW1=3; ib1=4; ig1=5; ibe1=6; im1=7; iv1=8;
    iWl=9; iWr=10; ibs=11; ig2=12; ibe2=13; im2=14; iv2=15;
    iWg=16; ias=17; iad=18; ibg=19; ig3=20; ibe3=21; im3=22; iv3=23;
    ipr=24; iWc=25; ibc=26; iWd1=27; ibd1=28; iWd2=29; ibd2=30;
  }else{
    iW1=3; ib1=4; iWl=5; iWr=6; ibs=7; iWg=8; ias=9; iad=10; ibg=11;
    ipr=12; iWc=13; ibc=14; iWd1=15; ibd1=16; iWd2=17; ibd2=18;
    ig1=19; ibe1=20; im1=21; iv1=22; ig2=23; ibe2=24; im2=25; iv2=26;
    ig3=27; ibe3=28; im3=29; iv3=30;
  }
  const float* W1 = (const float*)d_in[iW1];   const float* b1 = (const float*)d_in[ib1];
  const float* Wl = (const float*)d_in[iWl];   const float* Wr = (const float*)d_in[iWr];
  const float* bs = (const float*)d_in[ibs];   const float* Wg = (const float*)d_in[iWg];
  const float* a_src = (const float*)d_in[ias]; const float* a_dst = (const float*)d_in[iad];
  const float* bg = (const float*)d_in[ibg];   const float* protos = (const float*)d_in[ipr];
  const float* Wc = (const float*)d_in[iWc];   const float* bc = (const float*)d_in[ibc];
  const float* Wd1 = (const float*)d_in[iWd1]; const float* bd1 = (const float*)d_in[ibd1];
  const float* Wd2 = (const float*)d_in[iWd2]; const float* bd2 = (const float*)d_in[ibd2];
  const float* g1 = (const float*)d_in[ig1];   const float* be1 = (const float*)d_in[ibe1];
  const float* m1 = (const float*)d_in[im1];   const float* v1 = (const float*)d_in[iv1];
  const float* g2 = (const float*)d_in[ig2];   const float* be2 = (const float*)d_in[ibe2];
  const float* m2 = (const float*)d_in[im2];   const float* v2 = (const float*)d_in[iv2];
  const float* g3 = (const float*)d_in[ig3];   const float* be3 = (const float*)d_in[ibe3];
  const float* m3 = (const float*)d_in[im3];   const float* v3 = (const float*)d_in[iv3];

  const size_t NF = (size_t)N_*H_;
  const size_t intN = (size_t)N_ + (N_+1) + N_ + 2*(size_t)E_ + 128;
  const size_t fltN = (size_t)E_ + 3*(size_t)E_ + (size_t)7*N_ + G_*H_ + G_;
  const size_t NEED = NF*2*3 + (size_t)N_*384*2 + intN*4 + fltN*4 + (size_t)6*16384*2;
  if(ws_size < NEED){
    k_sentinel<<<1,1,0,stream>>>((float*)d_out, 1000.f + (float)(ws_size>>20));
    return;
  }
  bf16* RA = (bf16*)d_ws;            // h -> h2
  bf16* RB = RA + NF;                // h1
  bf16* RC = RB + NF;                // mean_nb -> h3
  bf16* HG3 = RC + NF;               // N x 384 (3 heads)
  int*  cnt     = (int*)(HG3 + (size_t)N_*384);
  int*  row_ptr = cnt + N_;
  int*  tmp     = row_ptr + (N_+1);
  int*  esrc    = tmp + N_;
  int*  edst    = esrc + E_;
  int*  bsum    = edst + E_;
  int*  boff    = bsum + 64;
  float* cg     = (float*)(boff + 64);   // E
  float* ew3    = cg + E_;               // 3E
  float* dinv   = ew3 + (size_t)3*E_;
  float* als3   = dinv + N_;             // N*3
  float* ald3   = als3 + (size_t)N_*3;
  float* pooled = ald3 + (size_t)N_*3;
  float* gcnt   = pooled + (size_t)G_*H_;
  unsigned short* WTg = (unsigned short*)(gcnt + G_);

  // ---- weight prep + CSR build ----
  k_wprep<<<(6*16384+255)/256, 256, 0, stream>>>(W1, Wl, Wr, Wg, WTg);
  hipMemsetAsync(cnt, 0, N_*sizeof(int), stream);
  k_count<<<(E_+255)/256, 256, 0, stream>>>(dst, cnt);
  k_scan1<<<NB_, 1024, 0, stream>>>(cnt, row_ptr, dinv, bsum);
  k_scan2<<<1, 64, 0, stream>>>(bsum, boff, row_ptr);
  k_scan3<<<(N_+255)/256, 256, 0, stream>>>(row_ptr, boff, tmp);
  k_scatter<<<(E_+255)/256, 256, 0, stream>>>(src, dst, dinv, tmp, esrc, edst, cg);

  const int GB = (N_+3)/4;
  const int MB = (N_+63)/64;
  // ---- GCN ----
  k_mm_x<<<MB, 256, 0, stream>>>(X, WTg, RA);
  k_gcn_gather<<<GB, 256, 0, stream>>>(row_ptr, esrc, cg, dinv, RA, b1, g1, be1, m1, v1, RB);
  // ---- SAGE ----
  k_sage_gather<<<GB, 256, 0, stream>>>(row_ptr, esrc, RB, RC);
  k_sage_mm<<<MB, 256, 0, stream>>>(RC, RB, WTg + 16384, WTg + 2*16384, bs, g2, be2, m2, v2, RA);
  // ---- GAT (all heads fused) ----
  k_gat_mm_all<<<MB, 256, 0, stream>>>(RA, WTg + 3*16384, a_src, a_dst, HG3, als3, ald3);
  k_ew<<<(E_+255)/256, 256, 0, stream>>>(esrc, edst, als3, ald3, ew3);
  k_gat_gather3<<<GB, 256, 0, stream>>>(row_ptr, esrc, ew3, als3, ald3, HG3, RC);
  // ---- pool + heads ----
  hipMemsetAsync(pooled, 0, (size_t)(G_*H_+G_)*sizeof(float), stream);
  {
    int waves = (N_ + NPW_ - 1)/NPW_;
    int blocks = (waves + 3)/4;
    k_h3fin_pool<<<blocks, 256, 0, stream>>>(RC, bg, g3, be3, m3, v3, batch, pooled, gcnt);
  }
  k_head<<<G_, 128, 0, stream>>>(pooled, gcnt, protos, Wc, bc, Wd1, bd1, Wd2, bd2, (float*)d_out);
}